// Round 4
// baseline (291.826 us; speedup 1.0000x reference)
//
#include <hip/hip_runtime.h>
#include <hip/hip_bf16.h>

typedef __attribute__((ext_vector_type(8))) short short8;
typedef __attribute__((ext_vector_type(4))) float f32x4;
typedef float float4a __attribute__((ext_vector_type(4), aligned(4)));
typedef unsigned short ushort4u __attribute__((ext_vector_type(4), aligned(2)));
typedef unsigned short ush;

#define MFMA_B16(a, b, c) __builtin_amdgcn_mfma_f32_16x16x32_bf16((a), (b), (c), 0, 0, 0)

__device__ __forceinline__ float bf2f(ush u) {
    union { unsigned int i; float f; } v; v.i = ((unsigned int)u) << 16; return v.f;
}
__device__ __forceinline__ ush f2bf(float f) {
    union { float f; unsigned int i; } v; v.f = f;
    unsigned int r = v.i + 0x7fffu + ((v.i >> 16) & 1u);
    return (ush)(r >> 16);
}
__device__ __forceinline__ float rcp_f(float x) { return __builtin_amdgcn_rcpf(x); }
__device__ __forceinline__ float sigm_pre(float x) {      // x = -log2(e)*(...)
    return rcp_f(1.0f + __builtin_amdgcn_exp2f(x));
}

// LDS-only barrier (2-wave producer/consumer sync in gru2). Global loads stay
// in flight across it (counted vmcnt at use, not drained at the barrier).
__device__ __forceinline__ void lds_barrier() {
    asm volatile("s_waitcnt lgkmcnt(0)" ::: "memory");
    __builtin_amdgcn_s_barrier();
    asm volatile("" ::: "memory");
}

// ---- dtype probes -----------------------------------------------------------
__device__ __forceinline__ bool probe_bf16(const ush* p, int tid, int* s_cnt) {
    if (tid == 0) *s_cnt = 0;
    __syncthreads();
    ush s = p[tid & 255];
    int e = (s >> 7) & 0xFF;
    if (tid < 256 && e >= 117 && e <= 137) atomicAdd(s_cnt, 1);
    __syncthreads();
    return *s_cnt >= 200;
}
__device__ __forceinline__ bool probe_bf16_64(const ush* p, int lane, int* s_cnt) {
    if (lane == 0) *s_cnt = 0;
    __syncthreads();
    int c = 0;
#pragma unroll
    for (int k = 0; k < 4; ++k) {
        ush s = p[lane * 4 + k];
        int e = (s >> 7) & 0xFF;
        c += (e >= 117 && e <= 137) ? 1 : 0;
    }
    atomicAdd(s_cnt, c);
    __syncthreads();
    return *s_cnt >= 200;
}

// ---------------------------------------------------------------------------
// Convert 20 weight/bias tensors to bf16 arena with gate scale folding.
// Tensors 0..15 are GRU (last dim 192): cols 0..127 (z,r) scaled by -log2(e);
// cols 128..191 scaled by 2*log2(e) for d2 (tanh) tensors (8..15).
// ---------------------------------------------------------------------------
struct WArgs {
    const void* src[20];
    int off[21];
};

__global__ __launch_bounds__(256)
void convert_w(WArgs a, ush* __restrict__ arena, const ush* __restrict__ probe)
{
    __shared__ int cnt;
    const bool bf = probe_bf16(probe, threadIdx.x, &cnt);
    const int total = a.off[20];
    for (int i = blockIdx.x * 256 + threadIdx.x; i < total; i += gridDim.x * 256) {
        int t = 0;
        while (t < 19 && i >= a.off[t + 1]) ++t;
        const int local = i - a.off[t];
        float v = bf ? bf2f(((const ush*)a.src[t])[local])
                     : ((const float*)a.src[t])[local];
        if (t < 16) {
            const int col = local % 192;
            if (col < 128) v *= -1.4426950408889634f;
            else if (t >= 8) v *= 2.885390081777927f;
        }
        arena[i] = f2bf(v);
    }
}

// ---- per-lane x loading for gru1 -------------------------------------------
struct XR { float4a f; ushort4u h; };

__device__ __forceinline__ XR loadx(const void* X, bool xbf, size_t row72, int tx, int q) {
    XR r;
    r.f = (float4a){0.f, 0.f, 0.f, 0.f};
    r.h = (ushort4u){0, 0, 0, 0};
    if (xbf) {
        const ush* p = (const ush*)X + (row72 + (size_t)tx) * 9 + q * 4;
        if (q < 2) r.h = *(const ushort4u*)p;
        else if (q == 2) r.h[0] = p[0];
    } else {
        const float* p = (const float*)X + (row72 + (size_t)tx) * 9 + q * 4;
        if (q < 2) r.f = *(const float4a*)p;
        else if (q == 2) r.f[0] = p[0];
    }
    return r;
}

__device__ __forceinline__ short8 convx(bool xbf, float4a rf, ushort4u rh) {
    short8 r;
    if (xbf) {
#pragma unroll
        for (int j = 0; j < 4; ++j) { r[2 * j] = (short)rh[j]; r[2 * j + 1] = 0; }
    } else {
#pragma unroll
        for (int j = 0; j < 4; ++j) {
            ush hi = f2bf(rf[j]);
            ush lo = f2bf(rf[j] - bf2f(hi));
            r[2 * j] = (short)hi; r[2 * j + 1] = (short)lo;
        }
    }
    return r;
}

// ---------------------------------------------------------------------------
// Layer 1: bidirectional GRU(64), relu candidate. ONE wave per 16 batch rows,
// all 64 units in-wave (bU/bW in registers). h-exchange is a wave-private LDS
// round-trip (DS ops are in-order per wave) -> ZERO barriers in the time loop.
// Explicit two-step bodies: even/odd x pipelines statically named.
// NOTE: the x-frag is snapshotted (axu_) BEFORE the pipeline rotation — the
// R3 bug was overwriting AX with x(t+2) before the MFMAs consumed x(t).
// grid: (bchunk/16, 2), block 64.
// ---------------------------------------------------------------------------
#define GRU1_STEP(T, AX, RFO, RHO)                                              \
    do {                                                                        \
        const short8 axu_ = AX;                     /* x(T) — use this */       \
        if ((T) < 70) AX = convx(xbf, RFO, RHO);    /* rotate: x((T)+2) */      \
        if ((T) < 68) {                                                         \
            XR rr = loadx(X, xbf, row72, dir ? 67 - (T) : (T) + 4, q);          \
            RFO = rr.f; RHO = rr.h;                                             \
        }                                                                       \
        short8 a0 = *(const short8*)&Ah[ln][q * 8];                             \
        short8 a1 = *(const short8*)&Ah[ln][32 + q * 8];                        \
        if ((T) > 0) {                                                          \
            const int tw = dir ? 71 - ((T) - 1) : (T) - 1;                      \
            ush* sp = seq + ((size_t)tw * bchunk + lb0 + ln) * 128 + dir * 64;  \
            *(short8*)(sp + q * 8) = a0;                                        \
            *(short8*)(sp + 32 + q * 8) = a1;                                   \
        }                                                                       \
        f32x4 az[4], ar[4], ahx[4], ahr[4];                                     \
        _Pragma("unroll") for (int n = 0; n < 4; ++n) {                         \
            az[n]  = MFMA_B16(axu_, bW[0][n], Cz[n]);                           \
            az[n]  = MFMA_B16(a0, bU[0][0][n], az[n]);                          \
            az[n]  = MFMA_B16(a1, bU[0][1][n], az[n]);                          \
            ar[n]  = MFMA_B16(axu_, bW[1][n], Cr[n]);                           \
            ar[n]  = MFMA_B16(a0, bU[1][0][n], ar[n]);                          \
            ar[n]  = MFMA_B16(a1, bU[1][1][n], ar[n]);                          \
            ahx[n] = MFMA_B16(axu_, bW[2][n], Chx[n]);                          \
            ahr[n] = MFMA_B16(a0, bU[2][0][n], Chr[n]);                         \
            ahr[n] = MFMA_B16(a1, bU[2][1][n], ahr[n]);                         \
        }                                                                       \
        _Pragma("unroll") for (int n = 0; n < 4; ++n)                           \
            _Pragma("unroll") for (int i = 0; i < 4; ++i) {                     \
                float z = sigm_pre(az[n][i]);                                   \
                float r = sigm_pre(ar[n][i]);                                   \
                float pre = ahx[n][i] + r * ahr[n][i];                          \
                float hh = fmaxf(pre, 0.0f);                                    \
                float hn = hh + z * (hreg[n][i] - hh);                          \
                hreg[n][i] = hn;                                                \
                Ah[q * 4 + i][n * 16 + ln] = f2bf(hn);                          \
            }                                                                   \
    } while (0)

__global__ __launch_bounds__(64, 1)
void gru1_kernel(const void* __restrict__ X, const void* __restrict__ h0f,
                 const void* __restrict__ h0b, int cb, int bchunk,
                 const ush* __restrict__ Wf, const ush* __restrict__ Uf,
                 const ush* __restrict__ bif, const ush* __restrict__ brf,
                 const ush* __restrict__ Wb, const ush* __restrict__ Ub,
                 const ush* __restrict__ bib, const ush* __restrict__ brb,
                 ush* __restrict__ seq)
{
    const int lane = threadIdx.x & 63;
    const int q = lane >> 4, ln = lane & 15;
    const int dir = blockIdx.y;
    const int lb0 = blockIdx.x * 16;
    const int gb0 = cb + lb0;

    const ush* W  = dir ? Wb  : Wf;
    const ush* U  = dir ? Ub  : Uf;
    const ush* bi = dir ? bib : bif;
    const ush* br = dir ? brb : brf;
    const void* h0 = dir ? h0b : h0f;

    __shared__ __align__(16) ush Ah[16][72];
    __shared__ int s_cnt;

    const bool xbf = probe_bf16_64((const ush*)X, lane, &s_cnt);

    // weights in registers: all 64 units for this wave
    short8 bU[3][2][4];
    short8 bW[3][4];
#pragma unroll
    for (int g = 0; g < 3; ++g)
#pragma unroll
        for (int n = 0; n < 4; ++n) {
            const int col = g * 64 + n * 16 + ln;
#pragma unroll
            for (int ks = 0; ks < 2; ++ks) {
                short8 f;
#pragma unroll
                for (int j = 0; j < 8; ++j) {
                    int kp = ks * 32 + q * 8 + j;
                    f[j] = (short)U[(size_t)kp * 192 + col];
                }
                bU[g][ks][n] = f;
            }
            short8 fw;
#pragma unroll
            for (int j = 0; j < 8; ++j) {
                int kp = q * 8 + j;
                fw[j] = (kp < 18) ? (short)W[(size_t)(kp >> 1) * 192 + col] : (short)0;
            }
            bW[g][n] = fw;
        }

    f32x4 Cz[4], Cr[4], Chx[4], Chr[4];
#pragma unroll
    for (int n = 0; n < 4; ++n) {
        const int u2 = n * 16 + ln;
        const float bz  = bf2f(bi[u2]) + bf2f(br[u2]);
        const float brg = bf2f(bi[64 + u2]) + bf2f(br[64 + u2]);
        const float bih = bf2f(bi[128 + u2]);
        const float brh = bf2f(br[128 + u2]);
        Cz[n]  = (f32x4){bz, bz, bz, bz};
        Cr[n]  = (f32x4){brg, brg, brg, brg};
        Chx[n] = (f32x4){bih, bih, bih, bih};
        Chr[n] = (f32x4){brh, brh, brh, brh};
    }

    // h(0)
    float hreg[4][4];
#pragma unroll
    for (int n = 0; n < 4; ++n)
#pragma unroll
        for (int i = 0; i < 4; ++i) {
            size_t idx = (size_t)(gb0 + q * 4 + i) * 64 + n * 16 + ln;
            float hv = xbf ? bf2f(((const ush*)h0)[idx]) : ((const float*)h0)[idx];
            hreg[n][i] = hv;
            Ah[q * 4 + i][n * 16 + ln] = f2bf(hv);
        }

    // x pipeline: ax0/ax1 converted frags (t, t+1); rf/rh raw bits (t+2, t+3)
    const size_t row72 = (size_t)(gb0 + ln) * 72;
    XR r0 = loadx(X, xbf, row72, dir ? 71 : 0, q);
    XR r1 = loadx(X, xbf, row72, dir ? 70 : 1, q);
    XR r2 = loadx(X, xbf, row72, dir ? 69 : 2, q);
    XR r3 = loadx(X, xbf, row72, dir ? 68 : 3, q);
    short8 ax0 = convx(xbf, r0.f, r0.h);
    short8 ax1 = convx(xbf, r1.f, r1.h);
    float4a rf0 = r2.f; ushort4u rh0 = r2.h;
    float4a rf1 = r3.f; ushort4u rh1 = r3.h;

    for (int t = 0; t < 72; t += 2) {
        GRU1_STEP(t,     ax0, rf0, rh0);
        GRU1_STEP(t + 1, ax1, rf1, rh1);
    }

    // final output h(72) -> seq
    {
        short8 a0 = *(const short8*)&Ah[ln][q * 8];
        short8 a1 = *(const short8*)&Ah[ln][32 + q * 8];
        const int tw = dir ? 0 : 71;
        ush* sp = seq + ((size_t)tw * bchunk + lb0 + ln) * 128 + dir * 64;
        *(short8*)(sp + q * 8) = a0;
        *(short8*)(sp + 32 + q * 8) = a1;
    }
}

// ---------------------------------------------------------------------------
// Layer 2: bidirectional GRU(64), tanh (pre-scaled). Producer/consumer wave
// pair per 16 batch rows: wave0 computes x-projections P(t+1) (bV in regs,
// seq prefetch depth 3) into double-buffered LDS; wave1 does recurrence+gates
// only (h wave-private). One 2-wave LDS barrier per step; the h-chain never
// crosses it. grid (bchunk/16, 2), block 128.
// ---------------------------------------------------------------------------
#define PROD_STEP(FA, BUFI, T)                                                 \
    do {                                                                       \
        if ((T) < 71) {                                                        \
            _Pragma("unroll") for (int g = 0; g < 3; ++g) {                    \
                _Pragma("unroll") for (int n = 0; n < 4; ++n) {                \
                    f32x4 acc = MFMA_B16(FA[0], bV[g][0][n], Cg[g][n]);        \
                    acc = MFMA_B16(FA[1], bV[g][1][n], acc);                   \
                    acc = MFMA_B16(FA[2], bV[g][2][n], acc);                   \
                    acc = MFMA_B16(FA[3], bV[g][3][n], acc);                   \
                    *(f32x4*)&Pbuf[BUFI][g][n][poff] = acc;                    \
                }                                                              \
            }                                                                  \
        }                                                                      \
        if ((T) < 69) {                                                        \
            const ush* sp = sptr0 + (long long)((T) + 3) * tstride;            \
            FA[0] = *(const short8*)sp;                                        \
            FA[1] = *(const short8*)(sp + 32);                                 \
            FA[2] = *(const short8*)(sp + 64);                                 \
            FA[3] = *(const short8*)(sp + 96);                                 \
        }                                                                      \
    } while (0)

#define CONS_STEP(BUFI, T)                                                     \
    do {                                                                       \
        f32x4 Pz[4], Pr[4], Pc[4];                                             \
        _Pragma("unroll") for (int n = 0; n < 4; ++n) {                        \
            Pz[n] = *(const f32x4*)&Pbuf[BUFI][0][n][poff];                    \
            Pr[n] = *(const f32x4*)&Pbuf[BUFI][1][n][poff];                    \
            Pc[n] = *(const f32x4*)&Pbuf[BUFI][2][n][poff];                    \
        }                                                                      \
        short8 a0 = *(const short8*)&Ah[ln][q * 8];                            \
        short8 a1 = *(const short8*)&Ah[ln][32 + q * 8];                       \
        f32x4 az[4], ar[4], ahr[4];                                            \
        _Pragma("unroll") for (int n = 0; n < 4; ++n) {                        \
            az[n]  = MFMA_B16(a0, bU[0][0][n], Pz[n]);                         \
            az[n]  = MFMA_B16(a1, bU[0][1][n], az[n]);                         \
            ar[n]  = MFMA_B16(a0, bU[1][0][n], Pr[n]);                         \
            ar[n]  = MFMA_B16(a1, bU[1][1][n], ar[n]);                         \
            ahr[n] = MFMA_B16(a0, bU[2][0][n], Chr[n]);                        \
            ahr[n] = MFMA_B16(a1, bU[2][1][n], ahr[n]);                        \
        }                                                                      \
        _Pragma("unroll") for (int n = 0; n < 4; ++n)                          \
            _Pragma("unroll") for (int i = 0; i < 4; ++i) {                    \
                float z = sigm_pre(az[n][i]);                                  \
                float r = sigm_pre(ar[n][i]);                                  \
                float pre = Pc[n][i] + r * ahr[n][i];                          \
                float e = __builtin_amdgcn_exp2f(pre);  /* pre-scaled */       \
                float hh = 1.0f - 2.0f * rcp_f(e + 1.0f);                      \
                float hn = hh + z * (hreg[n][i] - hh);                         \
                hreg[n][i] = hn;                                               \
                Ah[q * 4 + i][n * 16 + ln] = f2bf(hn);                         \
            }                                                                  \
    } while (0)

__global__ __launch_bounds__(128, 1)
void gru2_kernel(const ush* __restrict__ seq, int cb, int bchunk,
                 const ush* __restrict__ W2f, const ush* __restrict__ U2f,
                 const ush* __restrict__ bi2f, const ush* __restrict__ br2f,
                 const ush* __restrict__ W2b, const ush* __restrict__ U2b,
                 const ush* __restrict__ bi2b, const ush* __restrict__ br2b,
                 float* __restrict__ feat)
{
    const int tid = threadIdx.x;
    const int wv = tid >> 6, lane = tid & 63, q = lane >> 4, ln = lane & 15;
    const int dir = blockIdx.y, lb0 = blockIdx.x * 16, gb0 = cb + lb0;

    const ush* W  = dir ? W2b  : W2f;
    const ush* U  = dir ? U2b  : U2f;
    const ush* bi = dir ? bi2b : bi2f;
    const ush* br = dir ? br2b : br2f;

    // Pbuf: per (buf,gate,ntile): 8 groups of (8 lanes x 16B) + 16B pad
    __shared__ __align__(16) float Pbuf[2][3][4][288];
    __shared__ __align__(16) ush Ah[16][72];

    const int poff = (lane >> 3) * 36 + (lane & 7) * 4;

    if (wv == 0) {
        // ---------------- producer ----------------
        short8 bV[3][4][4];
#pragma unroll
        for (int g = 0; g < 3; ++g)
#pragma unroll
            for (int n = 0; n < 4; ++n) {
                const int col = g * 64 + n * 16 + ln;
#pragma unroll
                for (int ks = 0; ks < 4; ++ks) {
                    short8 f;
#pragma unroll
                    for (int j = 0; j < 8; ++j) {
                        int kp = ks * 32 + q * 8 + j;
                        f[j] = (short)W[(size_t)kp * 192 + col];
                    }
                    bV[g][ks][n] = f;
                }
            }
        f32x4 Cg[3][4];
#pragma unroll
        for (int n = 0; n < 4; ++n) {
            const int u2 = n * 16 + ln;
            const float bz  = bf2f(bi[u2]) + bf2f(br[u2]);
            const float brg = bf2f(bi[64 + u2]) + bf2f(br[64 + u2]);
            const float bih = bf2f(bi[128 + u2]);
            Cg[0][n] = (f32x4){bz, bz, bz, bz};
            Cg[1][n] = (f32x4){brg, brg, brg, brg};
            Cg[2][n] = (f32x4){bih, bih, bih, bih};
        }

        const long long tstride = (long long)bchunk * 128 * (dir ? -1 : 1);
        const ush* sptr0 = seq + (size_t)(lb0 + ln) * 128 + q * 8
                         + (dir ? 71ll * bchunk * 128 : 0);

        // P(0) -> buf0
        {
            const ush* sp = sptr0;
            short8 s0 = *(const short8*)sp;
            short8 s1 = *(const short8*)(sp + 32);
            short8 s2 = *(const short8*)(sp + 64);
            short8 s3 = *(const short8*)(sp + 96);
#pragma unroll
            for (int g = 0; g < 3; ++g)
#pragma unroll
                for (int n = 0; n < 4; ++n) {
                    f32x4 acc = MFMA_B16(s0, bV[g][0][n], Cg[g][n]);
                    acc = MFMA_B16(s1, bV[g][1][n], acc);
                    acc = MFMA_B16(s2, bV[g][2][n], acc);
                    acc = MFMA_B16(s3, bV[g][3][n], acc);
                    *(f32x4*)&Pbuf[0][g][n][poff] = acc;
                }
        }
        short8 F0[4], F1[4];
        {
            const ush* sp = sptr0 + tstride;
            F0[0] = *(const short8*)sp;        F0[1] = *(const short8*)(sp + 32);
            F0[2] = *(const short8*)(sp + 64); F0[3] = *(const short8*)(sp + 96);
        }
        {
            const ush* sp = sptr0 + 2 * tstride;
            F1[0] = *(const short8*)sp;        F1[1] = *(const short8*)(sp + 32);
            F1[2] = *(const short8*)(sp + 64); F1[3] = *(const short8*)(sp + 96);
        }
        lds_barrier();

        for (int t = 0; t < 72; t += 2) {
            PROD_STEP(F0, 1, t);
            lds_barrier();
            PROD_STEP(F1, 0, t + 1);
            lds_barrier();
        }
    } else {
        // ---------------- consumer ----------------
        short8 bU[3][2][4];
#pragma unroll
        for (int g = 0; g < 3; ++g)
#pragma unroll
            for (int n = 0; n < 4; ++n) {
                const int col = g * 64 + n * 16 + ln;
#pragma unroll
                for (int ks = 0; ks < 2; ++ks) {
                    short8 f;
#pragma unroll
                    for (int j = 0; j < 8; ++j) {
                        int kp = ks * 32 + q * 8 + j;
                        f[j] = (short)U[(size_t)kp * 192 + col];
                    }
                    bU[g][ks][n] = f;
                }
            }
        f32x4 Chr[4];
#pragma unroll
        for (int n = 0; n < 4; ++n) {
            const float brh = bf2f(br[128 + n * 16 + ln]);
            Chr[n] = (f32x4){brh, brh, brh, brh};
        }

        // h(0) = 0
        for (int i = lane; i < 16 * 72; i += 64) (&Ah[0][0])[i] = 0;
        float hreg[4][4];
#pragma unroll
        for (int n = 0; n < 4; ++n)
#pragma unroll
            for (int i = 0; i < 4; ++i) hreg[n][i] = 0.0f;
        lds_barrier();

        for (int t = 0; t < 72; t += 2) {
            CONS_STEP(0, t);
            lds_barrier();
            CONS_STEP(1, t + 1);
            lds_barrier();
        }

#pragma unroll
        for (int n = 0; n < 4; ++n)
#pragma unroll
            for (int i = 0; i < 4; ++i)
                feat[(size_t)(gb0 + q * 4 + i) * 128 + dir * 64 + n * 16 + ln] = hreg[n][i];
    }
}

// ---------------------------------------------------------------------------
__global__ __launch_bounds__(256, 1)
void head_kernel(const float* __restrict__ feat,
                 const ush* __restrict__ dW, const ush* __restrict__ db,
                 const ush* __restrict__ oW, const ush* __restrict__ ob,
                 float* __restrict__ out)
{
    const int tid = threadIdx.x;
    const int b0  = blockIdx.x * 16;

    __shared__ __align__(16) ush Wl[128][136];
    __shared__ __align__(16) float fs[16][128];
    __shared__ __align__(16) float hs[16][136];
    __shared__ __align__(16) float ls[16][32];

    for (int i = tid; i < 2048; i += 256) {
        const int k = i >> 4;
        const int c = (i & 15) * 8;
        *(int4*)&Wl[k][c] = *(const int4*)(dW + (size_t)k * 128 + c);
    }
    {
        const float4* src = (const float4*)(feat + (size_t)b0 * 128);
        float4* dst = (float4*)&fs[0][0];
        for (int i = tid; i < 512; i += 256) dst[i] = src[i];
    }
    __syncthreads();

    {
        const int row = tid >> 4;
        const int j0  = (tid & 15) * 8;
        float acc[8];
#pragma unroll
        for (int jj = 0; jj < 8; ++jj) acc[jj] = bf2f(db[j0 + jj]);
        for (int k = 0; k < 128; ++k) {
            float f = fs[row][k];
            short8 w = *(const short8*)&Wl[k][j0];
#pragma unroll
            for (int jj = 0; jj < 8; ++jj)
                acc[jj] += f * bf2f((ush)w[jj]);
        }
#pragma unroll
        for (int jj = 0; jj < 8; ++jj) hs[row][j0 + jj] = fmaxf(acc[jj], 0.0f);
    }
    __syncthreads();

    for (int e = tid; e < 16 * 24; e += 256) {
        const int row = e / 24, l = e - 24 * row;
        float acc = bf2f(ob[l]);
        for (int k = 0; k < 128; ++k)
            acc += hs[row][k] * bf2f(oW[(size_t)k * 24 + l]);
        ls[row][l] = acc;
    }
    __syncthreads();

    for (int e = tid; e < 16 * 24; e += 256) {
        const int row = e / 24, l = e - 24 * row;
        float mx = ls[row][0];
#pragma unroll
        for (int k = 1; k < 24; ++k) mx = fmaxf(mx, ls[row][k]);
        float s = 0.0f;
#pragma unroll
        for (int k = 0; k < 24; ++k) s += __expf(ls[row][k] - mx);
        float v = __expf(ls[row][l] - mx) * rcp_f(s);
        out[(size_t)(b0 + row) * 24 + l] = v;
    }
}

// ---------------------------------------------------------------------------
extern "C" void kernel_launch(void* const* d_in, const int* in_sizes, int n_in,
                              void* d_out, int out_size, void* d_ws, size_t ws_size,
                              hipStream_t stream) {
    (void)in_sizes; (void)n_in; (void)out_size;

    static const int wc[20] = {
        1728, 12288, 192, 192,     // d1f W,U,bi,br   (t 0..3)
        1728, 12288, 192, 192,     // d1b             (t 4..7)
        24576, 12288, 192, 192,    // d2f             (t 8..11)
        24576, 12288, 192, 192,    // d2b             (t 12..15)
        16384, 128,                // dense           (t 16,17)
        3072, 24                   // out             (t 18,19)
    };

    WArgs a;
    int off = 0;
    for (int t = 0; t < 20; ++t) {
        a.src[t] = d_in[t + 3];
        a.off[t] = off;
        off += wc[t];
    }
    a.off[20] = off;                         // 122,904 elements

    const unsigned long long arena_bytes = 245952ull;
    const unsigned long long feat_bytes  = 4096ull * 128ull * 4ull;
    const unsigned long long seq_full    = 72ull * 4096ull * 128ull * 2ull;
    const unsigned long long fixed       = arena_bytes + feat_bytes;

    int nc = 32;
    for (int c = 1; c <= 32; c *= 2) {
        if (fixed + seq_full / (unsigned long long)c <= (unsigned long long)ws_size) { nc = c; break; }
    }
    const int bchunk = 4096 / nc;

    ush* arena  = (ush*)d_ws;
    float* feat = (float*)((char*)d_ws + arena_bytes);
    ush* seq    = (ush*)((char*)d_ws + fixed);

    convert_w<<<128, 256, 0, stream>>>(a, arena, (const ush*)d_in[0]);

    const ush* d1fW = arena + a.off[0];
    const ush* d1fU = arena + a.off[1];
    const ush* d1fbi= arena + a.off[2];
    const ush* d1fbr= arena + a.off[3];
    const ush* d1bW = arena + a.off[4];
    const ush* d1bU = arena + a.off[5];
    const ush* d1bbi= arena + a.off[6];
    const ush* d1bbr= arena + a.off[7];
    const ush* d2fW = arena + a.off[8];
    const ush* d2fU = arena + a.off[9];
    const ush* d2fbi= arena + a.off[10];
    const ush* d2fbr= arena + a.off[11];
    const ush* d2bW = arena + a.off[12];
    const ush* d2bU = arena + a.off[13];
    const ush* d2bbi= arena + a.off[14];
    const ush* d2bbr= arena + a.off[15];
    const ush* dW   = arena + a.off[16];
    const ush* db   = arena + a.off[17];
    const ush* oW   = arena + a.off[18];
    const ush* ob   = arena + a.off[19];

    for (int c = 0; c < nc; ++c) {
        const int cb = c * bchunk;
        gru1_kernel<<<dim3(bchunk / 16, 2), 64, 0, stream>>>(
            d_in[0], d_in[1], d_in[2], cb, bchunk,
            d1fW, d1fU, d1fbi, d1fbr, d1bW, d1bU, d1bbi, d1bbr, seq);
        gru2_kernel<<<dim3(bchunk / 16, 2), 128, 0, stream>>>(
            seq, cb, bchunk,
            d2fW, d2fU, d2fbi, d2fbr, d2bW, d2bU, d2bbi, d2bbr, feat);
    }
    head_kernel<<<256, 256, 0, stream>>>(
        feat, dW, db, oW, ob, (float*)d_out);
}

// Round 5
// 242.622 us; speedup vs baseline: 1.2028x; 1.2028x over previous
//
#include <hip/hip_runtime.h>
#include <hip/hip_bf16.h>

typedef __attribute__((ext_vector_type(8))) short short8;
typedef __attribute__((ext_vector_type(4))) float f32x4;
typedef float float4a __attribute__((ext_vector_type(4), aligned(4)));
typedef unsigned short ushort4u __attribute__((ext_vector_type(4), aligned(2)));
typedef unsigned short ush;

#define MFMA_B16(a, b, c) __builtin_amdgcn_mfma_f32_16x16x32_bf16((a), (b), (c), 0, 0, 0)

__device__ __forceinline__ float bf2f(ush u) {
    union { unsigned int i; float f; } v; v.i = ((unsigned int)u) << 16; return v.f;
}
__device__ __forceinline__ ush f2bf(float f) {
    union { float f; unsigned int i; } v; v.f = f;
    unsigned int r = v.i + 0x7fffu + ((v.i >> 16) & 1u);
    return (ush)(r >> 16);
}
// fast HW transcendentals (1 inst each). Gate scale constants folded into the
// weights at convert time: z/r pre-acts arrive pre-multiplied by -log2(e),
// gru2 candidate pre-acts by 2*log2(e).
__device__ __forceinline__ float rcp_f(float x) { return __builtin_amdgcn_rcpf(x); }
__device__ __forceinline__ float sigm_pre(float x) {      // x = -log2(e)*(...)
    return rcp_f(1.0f + __builtin_amdgcn_exp2f(x));
}
__device__ __forceinline__ float tanh_pre(float x) {      // x = 2*log2(e)*(...)
    return 1.0f - 2.0f * rcp_f(__builtin_amdgcn_exp2f(x) + 1.0f);
}

// LDS-only barrier: __syncthreads() would drain vmcnt(0) too; cross-wave
// traffic in the GRU loops is LDS-only (Ah), so lgkmcnt(0)+s_barrier suffices
// and global prefetch/stores stay in flight across steps.
__device__ __forceinline__ void lds_barrier() {
    asm volatile("s_waitcnt lgkmcnt(0)" ::: "memory");
    __builtin_amdgcn_s_barrier();
    asm volatile("" ::: "memory");
}

// probe 256 shorts: bf16 vs fp32 discrimination (deterministic per call)
__device__ __forceinline__ bool probe_bf16(const ush* p, int tid, int* s_cnt) {
    if (tid == 0) *s_cnt = 0;
    __syncthreads();
    ush s = p[tid & 255];
    int e = (s >> 7) & 0xFF;
    if (tid < 256 && e >= 117 && e <= 137) atomicAdd(s_cnt, 1);
    __syncthreads();
    return *s_cnt >= 200;
}

// ---------------------------------------------------------------------------
// Convert 20 weight/bias tensors to bf16 arena with gate scale folding.
// Tensors 0..15 are GRU (last dim 192): cols 0..127 (z,r) scaled by -log2(e);
// cols 128..191 scaled by 2*log2(e) for d2 (tanh) tensors (8..15).
// ---------------------------------------------------------------------------
struct WArgs {
    const void* src[20];
    int off[21];
};

__global__ __launch_bounds__(256)
void convert_w(WArgs a, ush* __restrict__ arena, const ush* __restrict__ probe)
{
    __shared__ int cnt;
    const bool bf = probe_bf16(probe, threadIdx.x, &cnt);
    const int total = a.off[20];
    for (int i = blockIdx.x * 256 + threadIdx.x; i < total; i += gridDim.x * 256) {
        int t = 0;
        while (t < 19 && i >= a.off[t + 1]) ++t;
        const int local = i - a.off[t];
        float v = bf ? bf2f(((const ush*)a.src[t])[local])
                     : ((const float*)a.src[t])[local];
        if (t < 16) {
            const int col = local % 192;
            if (col < 128) v *= -1.4426950408889634f;
            else if (t >= 8) v *= 2.885390081777927f;
        }
        arena[i] = f2bf(v);
    }
}

// ---- per-lane x loading for gru1 -------------------------------------------
// lane (q,ln) supplies A-frag K-positions q*8..q*8+7 = hi/lo pairs of features
// 4q..4q+3 for batch row ln. q=3 all-zero (only 9 features); q=2 one feature.
struct XR { float4a f; ushort4u h; };

__device__ __forceinline__ XR loadx(const void* X, bool xbf, size_t row72, int tx, int q) {
    XR r;
    r.f = (float4a){0.f, 0.f, 0.f, 0.f};
    r.h = (ushort4u){0, 0, 0, 0};
    if (xbf) {
        const ush* p = (const ush*)X + (row72 + (size_t)tx) * 9 + q * 4;
        if (q < 2) r.h = *(const ushort4u*)p;
        else if (q == 2) r.h[0] = p[0];
    } else {
        const float* p = (const float*)X + (row72 + (size_t)tx) * 9 + q * 4;
        if (q < 2) r.f = *(const float4a*)p;
        else if (q == 2) r.f[0] = p[0];
    }
    return r;
}

__device__ __forceinline__ short8 convx(bool xbf, float4a rf, ushort4u rh) {
    short8 r;
    if (xbf) {
#pragma unroll
        for (int j = 0; j < 4; ++j) { r[2 * j] = (short)rh[j]; r[2 * j + 1] = 0; }
    } else {
#pragma unroll
        for (int j = 0; j < 4; ++j) {
            ush hi = f2bf(rf[j]);
            ush lo = f2bf(rf[j] - bf2f(hi));
            r[2 * j] = (short)hi; r[2 * j + 1] = (short)lo;
        }
    }
    return r;
}

// ---------------------------------------------------------------------------
// Layer 1: bidirectional GRU(64), relu candidate. 16 rows/block, 4 waves
// splitting the 64 units (16 each); h bf16 K=64 exchanged via double-buffered
// LDS + one LDS-only barrier/step. x path is per-lane direct global load +
// in-register hi/lo bf16 conversion (no x LDS staging; all 4 waves read the
// same 576B/step -> L1 hits). grid: (bchunk/16, 2), block 256.
// ---------------------------------------------------------------------------
__global__ __launch_bounds__(256, 1)
void gru1_kernel(const void* __restrict__ X, const void* __restrict__ h0f,
                 const void* __restrict__ h0b, int cb, int bchunk,
                 const ush* __restrict__ Wf, const ush* __restrict__ Uf,
                 const ush* __restrict__ bif, const ush* __restrict__ brf,
                 const ush* __restrict__ Wb, const ush* __restrict__ Ub,
                 const ush* __restrict__ bib, const ush* __restrict__ brb,
                 ush* __restrict__ seq)
{
    const int tid  = threadIdx.x;
    const int lane = tid & 63;
    const int wv   = tid >> 6;
    const int q    = lane >> 4;
    const int ln   = lane & 15;
    const int dir  = blockIdx.y;
    const int lb0  = blockIdx.x * 16;
    const int gb0  = cb + lb0;
    const int u    = wv * 16 + ln;

    const ush* W  = dir ? Wb  : Wf;
    const ush* U  = dir ? Ub  : Uf;
    const ush* bi = dir ? bib : bif;
    const ush* br = dir ? brb : brf;
    const void* h0 = dir ? h0b : h0f;

    __shared__ __align__(16) ush Ah[2][16][72];
    __shared__ int s_cnt;

    const bool xbf = probe_bf16((const ush*)X, tid, &s_cnt);

    short8 bU[3][2];
    short8 bW[3];
#pragma unroll
    for (int g = 0; g < 3; ++g) {
        const int col = g * 64 + u;
#pragma unroll
        for (int ks = 0; ks < 2; ++ks) {
            short8 f;
#pragma unroll
            for (int j = 0; j < 8; ++j) {
                int kp = ks * 32 + q * 8 + j;
                f[j] = (short)U[(size_t)kp * 192 + col];
            }
            bU[g][ks] = f;
        }
        short8 fw;
#pragma unroll
        for (int j = 0; j < 8; ++j) {
            int kp = q * 8 + j;
            fw[j] = (kp < 18) ? (short)W[(size_t)(kp >> 1) * 192 + col] : (short)0;
        }
        bW[g] = fw;
    }

    const float bz  = bf2f(bi[u])       + bf2f(br[u]);        // pre-scaled
    const float brg = bf2f(bi[64 + u])  + bf2f(br[64 + u]);   // pre-scaled
    const float bih = bf2f(bi[128 + u]);                      // unscaled (relu)
    const float brh = bf2f(br[128 + u]);
    const f32x4 Cz  = {bz,  bz,  bz,  bz};
    const f32x4 Cr  = {brg, brg, brg, brg};
    const f32x4 Chx = {bih, bih, bih, bih};
    const f32x4 Chr = {brh, brh, brh, brh};

    float hreg[4];
#pragma unroll
    for (int i = 0; i < 4; ++i) {
        int m = q * 4 + i;
        size_t idx = (size_t)(gb0 + m) * 64 + u;
        float hv = xbf ? bf2f(((const ush*)h0)[idx])
                       : ((const float*)h0)[idx];
        hreg[i] = hv;
        Ah[0][m][u] = f2bf(hv);
    }

    const int r2 = tid >> 3, c2 = tid & 7;

    // x pipeline: axc = converted frag for x(t); rn = raw bits of x(t+1)
    const size_t row72 = (size_t)(gb0 + ln) * 72;
    short8 axc;
    XR rn;
    {
        XR r0 = loadx(X, xbf, row72, dir ? 71 : 0, q);
        axc = convx(xbf, r0.f, r0.h);
        rn  = loadx(X, xbf, row72, dir ? 70 : 1, q);
    }
    __syncthreads();

#pragma unroll 2
    for (int t = 0; t < 72; ++t) {
        const int cur = t & 1, nb = cur ^ 1;

        // issue x(t+2) load early; latency spans the whole step
        XR rr;
        rr.f = (float4a){0.f, 0.f, 0.f, 0.f};
        rr.h = (ushort4u){0, 0, 0, 0};
        if (t < 70) rr = loadx(X, xbf, row72, dir ? 69 - t : t + 2, q);

        if (t > 0 && tid < 128) {
            const int tw = dir ? (71 - (t - 1)) : (t - 1);
            int4 v = *(const int4*)&Ah[cur][r2][c2 * 8];
            *(int4*)(seq + ((size_t)tw * bchunk + lb0 + r2) * 128 + dir * 64 + c2 * 8) = v;
        }

        const ush* ap = &Ah[cur][ln][0];
        short8 a0 = *(const short8*)(ap + q * 8);
        short8 a1 = *(const short8*)(ap + 32 + q * 8);
        f32x4 az  = MFMA_B16(axc, bW[0], Cz);
        az        = MFMA_B16(a0, bU[0][0], az);
        az        = MFMA_B16(a1, bU[0][1], az);
        f32x4 ar  = MFMA_B16(axc, bW[1], Cr);
        ar        = MFMA_B16(a0, bU[1][0], ar);
        ar        = MFMA_B16(a1, bU[1][1], ar);
        f32x4 ahx = MFMA_B16(axc, bW[2], Chx);
        f32x4 ahr = MFMA_B16(a0, bU[2][0], Chr);
        ahr       = MFMA_B16(a1, bU[2][1], ahr);

#pragma unroll
        for (int i = 0; i < 4; ++i) {
            const int m = q * 4 + i;
            float z = sigm_pre(az[i]);
            float r = sigm_pre(ar[i]);
            float pre = ahx[i] + r * ahr[i];
            float hh = fmaxf(pre, 0.0f);
            float hn = hh + z * (hreg[i] - hh);
            hreg[i] = hn;
            Ah[nb][m][u] = f2bf(hn);
        }

        // rotate x pipeline: build frag for t+1, keep raw t+2
        axc = convx(xbf, rn.f, rn.h);
        rn = rr;
        lds_barrier();
    }

    if (tid < 128) {
        const int tw = dir ? 0 : 71;
        int4 v = *(const int4*)&Ah[0][r2][c2 * 8];
        *(int4*)(seq + ((size_t)tw * bchunk + lb0 + r2) * 128 + dir * 64 + c2 * 8) = v;
    }
}

// ---------------------------------------------------------------------------
// Layer 2: bidirectional GRU(64), tanh (pre-scaled candidate). Per-lane seq
// A-frags direct from global, depth-3 prefetch (issue at t, consume at t+2);
// 12 projection MFMAs for t+1 from c regs, 6 recurrent + gates per step.
// In-loop barriers are LDS-only. grid (bchunk/16, 2).
// ---------------------------------------------------------------------------
__global__ __launch_bounds__(256, 1)
void gru2_kernel(const ush* __restrict__ seq, int cb, int bchunk,
                 const ush* __restrict__ W2f, const ush* __restrict__ U2f,
                 const ush* __restrict__ bi2f, const ush* __restrict__ br2f,
                 const ush* __restrict__ W2b, const ush* __restrict__ U2b,
                 const ush* __restrict__ bi2b, const ush* __restrict__ br2b,
                 float* __restrict__ feat)
{
    const int tid  = threadIdx.x;
    const int lane = tid & 63;
    const int wv   = tid >> 6;
    const int q    = lane >> 4;
    const int ln   = lane & 15;
    const int dir  = blockIdx.y;
    const int lb0  = blockIdx.x * 16;
    const int gb0  = cb + lb0;
    const int u    = wv * 16 + ln;

    const ush* W  = dir ? W2b  : W2f;
    const ush* U  = dir ? U2b  : U2f;
    const ush* bi = dir ? bi2b : bi2f;
    const ush* br = dir ? br2b : br2f;

    __shared__ __align__(16) ush Ah[2][16][72];

    {
        ush* p = &Ah[0][0][0];
        for (int i = tid; i < 16 * 72; i += 256) p[i] = 0;
    }

    const long long tstride = (long long)bchunk * 128 * (dir ? -1 : 1);
    const ush* sptr0 = seq + ((size_t)(lb0 + ln)) * 128 + q * 8
                     + (dir ? 71ll * bchunk * 128 : 0);

    short8 bU[3][2];
    short8 bV[3][4];
#pragma unroll
    for (int g = 0; g < 3; ++g) {
        const int col = g * 64 + u;
#pragma unroll
        for (int ks = 0; ks < 2; ++ks) {
            short8 f;
#pragma unroll
            for (int j = 0; j < 8; ++j) {
                int kp = ks * 32 + q * 8 + j;
                f[j] = (short)U[(size_t)kp * 192 + col];
            }
            bU[g][ks] = f;
        }
#pragma unroll
        for (int ks = 0; ks < 4; ++ks) {
            short8 fv;
#pragma unroll
            for (int j = 0; j < 8; ++j) {
                int kp = ks * 32 + q * 8 + j;
                fv[j] = (short)W[(size_t)kp * 192 + col];
            }
            bV[g][ks] = fv;
        }
    }

    const float bz  = bf2f(bi[u])       + bf2f(br[u]);        // pre-scaled
    const float brg = bf2f(bi[64 + u])  + bf2f(br[64 + u]);   // pre-scaled
    const float bih = bf2f(bi[128 + u]);                      // pre-scaled (tanh)
    const float brh = bf2f(br[128 + u]);
    const f32x4 Cz  = {bz,  bz,  bz,  bz};
    const f32x4 Cr  = {brg, brg, brg, brg};
    const f32x4 Chx = {bih, bih, bih, bih};
    const f32x4 Chr = {brh, brh, brh, brh};

    float hreg[4];
#pragma unroll
    for (int i = 0; i < 4; ++i) hreg[i] = 0.0f;

    f32x4 P0, P1, P2;
    {
        const ush* sp = sptr0;
        short8 s0 = *(const short8*)(sp);
        short8 s1 = *(const short8*)(sp + 32);
        short8 s2 = *(const short8*)(sp + 64);
        short8 s3 = *(const short8*)(sp + 96);
        P0 = MFMA_B16(s0, bV[0][0], Cz);
        P0 = MFMA_B16(s1, bV[0][1], P0);
        P0 = MFMA_B16(s2, bV[0][2], P0);
        P0 = MFMA_B16(s3, bV[0][3], P0);
        P1 = MFMA_B16(s0, bV[1][0], Cr);
        P1 = MFMA_B16(s1, bV[1][1], P1);
        P1 = MFMA_B16(s2, bV[1][2], P1);
        P1 = MFMA_B16(s3, bV[1][3], P1);
        P2 = MFMA_B16(s0, bV[2][0], Chx);
        P2 = MFMA_B16(s1, bV[2][1], P2);
        P2 = MFMA_B16(s2, bV[2][2], P2);
        P2 = MFMA_B16(s3, bV[2][3], P2);
    }
    // invariant at top of step t: c holds seq(t+1), g holds seq(t+2)
    short8 c0, c1, c2, c3, g0, g1, g2, g3;
    {
        const ush* sp = sptr0 + tstride;
        c0 = *(const short8*)(sp);
        c1 = *(const short8*)(sp + 32);
        c2 = *(const short8*)(sp + 64);
        c3 = *(const short8*)(sp + 96);
    }
    {
        const ush* sp = sptr0 + 2 * tstride;
        g0 = *(const short8*)(sp);
        g1 = *(const short8*)(sp + 32);
        g2 = *(const short8*)(sp + 64);
        g3 = *(const short8*)(sp + 96);
    }
    __syncthreads();

#pragma unroll 2
    for (int t = 0; t < 72; ++t) {
        const int cur = t & 1, nb = cur ^ 1;

        short8 f0 = g0, f1 = g1, f2 = g2, f3 = g3;
        if (t < 69) {
            const ush* sp = sptr0 + (long long)(t + 3) * tstride;
            f0 = *(const short8*)(sp);
            f1 = *(const short8*)(sp + 32);
            f2 = *(const short8*)(sp + 64);
            f3 = *(const short8*)(sp + 96);
        }

        const ush* ap = &Ah[cur][ln][0];
        short8 a0 = *(const short8*)(ap + q * 8);
        short8 a1 = *(const short8*)(ap + 32 + q * 8);
        f32x4 az  = MFMA_B16(a0, bU[0][0], P0);
        az        = MFMA_B16(a1, bU[0][1], az);
        f32x4 ar  = MFMA_B16(a0, bU[1][0], P1);
        ar        = MFMA_B16(a1, bU[1][1], ar);
        f32x4 ahr = MFMA_B16(a0, bU[2][0], Chr);
        ahr       = MFMA_B16(a1, bU[2][1], ahr);
        f32x4 ahx = P2;

#pragma unroll
        for (int i = 0; i < 4; ++i) {
            const int m = q * 4 + i;
            float z = sigm_pre(az[i]);
            float r = sigm_pre(ar[i]);
            float pre = ahx[i] + r * ahr[i];
            float hh = tanh_pre(pre);
            float hn = hh + z * (hreg[i] - hh);
            hreg[i] = hn;
            Ah[nb][m][u] = f2bf(hn);
        }

        if (t < 71) {
            P0 = MFMA_B16(c0, bV[0][0], Cz);
            P0 = MFMA_B16(c1, bV[0][1], P0);
            P0 = MFMA_B16(c2, bV[0][2], P0);
            P0 = MFMA_B16(c3, bV[0][3], P0);
            P1 = MFMA_B16(c0, bV[1][0], Cr);
            P1 = MFMA_B16(c1, bV[1][1], P1);
            P1 = MFMA_B16(c2, bV[1][2], P1);
            P1 = MFMA_B16(c3, bV[1][3], P1);
            P2 = MFMA_B16(c0, bV[2][0], Chx);
            P2 = MFMA_B16(c1, bV[2][1], P2);
            P2 = MFMA_B16(c2, bV[2][2], P2);
            P2 = MFMA_B16(c3, bV[2][3], P2);
        }
        c0 = g0; c1 = g1; c2 = g2; c3 = g3;
        g0 = f0; g1 = f1; g2 = f2; g3 = f3;
        lds_barrier();
    }

#pragma unroll
    for (int i = 0; i < 4; ++i) {
        const int m = q * 4 + i;
        feat[(size_t)(gb0 + m) * 128 + dir * 64 + u] = hreg[i];
    }
}

// ---------------------------------------------------------------------------
__global__ __launch_bounds__(256, 1)
void head_kernel(const float* __restrict__ feat,
                 const ush* __restrict__ dW, const ush* __restrict__ db,
                 const ush* __restrict__ oW, const ush* __restrict__ ob,
                 float* __restrict__ out)
{
    const int tid = threadIdx.x;
    const int b0  = blockIdx.x * 16;

    __shared__ __align__(16) ush Wl[128][136];
    __shared__ __align__(16) float fs[16][128];
    __shared__ __align__(16) float hs[16][136];
    __shared__ __align__(16) float ls[16][32];

    for (int i = tid; i < 2048; i += 256) {
        const int k = i >> 4;
        const int c = (i & 15) * 8;
        *(int4*)&Wl[k][c] = *(const int4*)(dW + (size_t)k * 128 + c);
    }
    {
        const float4* src = (const float4*)(feat + (size_t)b0 * 128);
        float4* dst = (float4*)&fs[0][0];
        for (int i = tid; i < 512; i += 256) dst[i] = src[i];
    }
    __syncthreads();

    {
        const int row = tid >> 4;
        const int j0  = (tid & 15) * 8;
        float acc[8];
#pragma unroll
        for (int jj = 0; jj < 8; ++jj) acc[jj] = bf2f(db[j0 + jj]);
        for (int k = 0; k < 128; ++k) {
            float f = fs[row][k];
            short8 w = *(const short8*)&Wl[k][j0];
#pragma unroll
            for (int jj = 0; jj < 8; ++jj)
                acc[jj] += f * bf2f((ush)w[jj]);
        }
#pragma unroll
        for (int jj = 0; jj < 8; ++jj) hs[row][j0 + jj] = fmaxf(acc[jj], 0.0f);
    }
    __syncthreads();

    for (int e = tid; e < 16 * 24; e += 256) {
        const int row = e / 24, l = e - 24 * row;
        float acc = bf2f(ob[l]);
        for (int k = 0; k < 128; ++k)
            acc += hs[row][k] * bf2f(oW[(size_t)k * 24 + l]);
        ls[row][l] = acc;
    }
    __syncthreads();

    for (int e = tid; e < 16 * 24; e += 256) {
        const int row = e / 24, l = e - 24 * row;
        float mx = ls[row][0];
#pragma unroll
        for (int k = 1; k < 24; ++k) mx = fmaxf(mx, ls[row][k]);
        float s = 0.0f;
#pragma unroll
        for (int k = 0; k < 24; ++k) s += __expf(ls[row][k] - mx);
        float v = __expf(ls[row][l] - mx) * rcp_f(s);
        out[(size_t)(b0 + row) * 24 + l] = v;
    }
}

// ---------------------------------------------------------------------------
extern "C" void kernel_launch(void* const* d_in, const int* in_sizes, int n_in,
                              void* d_out, int out_size, void* d_ws, size_t ws_size,
                              hipStream_t stream) {
    (void)in_sizes; (void)n_in; (void)out_size;

    static const int wc[20] = {
        1728, 12288, 192, 192,     // d1f W,U,bi,br   (t 0..3)
        1728, 12288, 192, 192,     // d1b             (t 4..7)
        24576, 12288, 192, 192,    // d2f             (t 8..11)
        24576, 12288, 192, 192,    // d2b             (t 12..15)
        16384, 128,                // dense           (t 16,17)
        3072, 24                   // out             (t 18,19)
    };

    WArgs a;
    int off = 0;
    for (int t = 0; t < 20; ++t) {
        a.src[t] = d_in[t + 3];
        a.off[t] = off;
        off += wc[t];
    }
    a.off[20] = off;                         // 122,904 elements

    const unsigned long long arena_bytes = 245952ull;
    const unsigned long long feat_bytes  = 4096ull * 128ull * 4ull;
    const unsigned long long seq_full    = 72ull * 4096ull * 128ull * 2ull;
    const unsigned long long fixed       = arena_bytes + feat_bytes;

    int nc = 32;
    for (int c = 1; c <= 32; c *= 2) {
        if (fixed + seq_full / (unsigned long long)c <= (unsigned long long)ws_size) { nc = c; break; }
    }
    const int bchunk = 4096 / nc;

    ush* arena  = (ush*)d_ws;
    float* feat = (float*)((char*)d_ws + arena_bytes);
    ush* seq    = (ush*)((char*)d_ws + fixed);

    convert_w<<<128, 256, 0, stream>>>(a, arena, (const ush*)d_in[0]);

    const ush* d1fW = arena + a.off[0];
    const ush* d1fU = arena + a.off[1];
    const ush* d1fbi= arena + a.off[2];
    const ush* d1fbr= arena + a.off[3];
    const ush* d1bW = arena + a.off[4];
    const ush* d1bU = arena + a.off[5];
    const ush* d1bbi= arena + a.off[6];
    const ush* d1bbr= arena + a.off[7];
    const ush* d2fW = arena + a.off[8];
    const ush* d2fU = arena + a.off[9];
    const ush* d2fbi= arena + a.off[10];
    const ush* d2fbr= arena + a.off[11];
    const ush* d2bW = arena + a.off[12];
    const ush* d2bU = arena + a.off[13];
    const ush* d2bbi= arena + a.off[14];
    const ush* d2bbr= arena + a.off[15];
    const ush* dW   = arena + a.off[16];
    const ush* db   = arena + a.off[17];
    const ush* oW   = arena + a.off[18];
    const ush* ob   = arena + a.off[19];

    for (int c = 0; c < nc; ++c) {
        const int cb = c * bchunk;
        gru1_kernel<<<dim3(bchunk / 16, 2), 256, 0, stream>>>(
            d_in[0], d_in[1], d_in[2], cb, bchunk,
            d1fW, d1fU, d1fbi, d1fbr, d1bW, d1bU, d1bbi, d1bbr, seq);
        gru2_kernel<<<dim3(bchunk / 16, 2), 256, 0, stream>>>(
            seq, cb, bchunk,
            d2fW, d2fU, d2fbi, d2fbr, d2bW, d2bU, d2bbi, d2bbr, feat);
    }
    head_kernel<<<256, 256, 0, stream>>>(
        feat, dW, db, oW, ob, (float*)d_out);
}

// Round 6
// 242.578 us; speedup vs baseline: 1.2030x; 1.0002x over previous
//
#include <hip/hip_runtime.h>
#include <hip/hip_bf16.h>

typedef __attribute__((ext_vector_type(8))) short short8;
typedef __attribute__((ext_vector_type(4))) float f32x4;
typedef unsigned short ush;

#define MFMA_B16(a, b, c) __builtin_amdgcn_mfma_f32_16x16x32_bf16((a), (b), (c), 0, 0, 0)

__device__ __forceinline__ float bf2f(ush u) {
    union { unsigned int i; float f; } v; v.i = ((unsigned int)u) << 16; return v.f;
}
__device__ __forceinline__ ush f2bf(float f) {
    union { float f; unsigned int i; } v; v.f = f;
    unsigned int r = v.i + 0x7fffu + ((v.i >> 16) & 1u);
    return (ush)(r >> 16);
}
// fast HW transcendentals. Gate scales folded into weights at convert time:
// z/r pre-acts pre-multiplied by -log2(e), gru2 candidate by 2*log2(e).
__device__ __forceinline__ float rcp_f(float x) { return __builtin_amdgcn_rcpf(x); }
__device__ __forceinline__ float sigm_pre(float x) {      // x = -log2(e)*(...)
    return rcp_f(1.0f + __builtin_amdgcn_exp2f(x));
}
__device__ __forceinline__ float tanh_pre(float x) {      // x = 2*log2(e)*(...)
    return 1.0f - 2.0f * rcp_f(__builtin_amdgcn_exp2f(x) + 1.0f);
}

// LDS-only barrier: cross-wave traffic in the GRU loops is LDS-only, so
// lgkmcnt(0)+s_barrier suffices; global loads/stores stay in flight across it.
__device__ __forceinline__ void lds_barrier() {
    asm volatile("s_waitcnt lgkmcnt(0)" ::: "memory");
    __builtin_amdgcn_s_barrier();
    asm volatile("" ::: "memory");
}

// probe 256 shorts: bf16 vs fp32 discrimination (deterministic per call)
__device__ __forceinline__ bool probe_bf16(const ush* p, int tid, int* s_cnt) {
    if (tid == 0) *s_cnt = 0;
    __syncthreads();
    ush s = p[tid & 255];
    int e = (s >> 7) & 0xFF;
    if (tid < 256 && e >= 117 && e <= 137) atomicAdd(s_cnt, 1);
    __syncthreads();
    return *s_cnt >= 200;
}

// ---------------------------------------------------------------------------
// Convert 20 weight/bias tensors to bf16 arena with gate scale folding.
// ---------------------------------------------------------------------------
struct WArgs {
    const void* src[20];
    int off[21];
};

__global__ __launch_bounds__(256)
void convert_w(WArgs a, ush* __restrict__ arena, const ush* __restrict__ probe)
{
    __shared__ int cnt;
    const bool bf = probe_bf16(probe, threadIdx.x, &cnt);
    const int total = a.off[20];
    for (int i = blockIdx.x * 256 + threadIdx.x; i < total; i += gridDim.x * 256) {
        int t = 0;
        while (t < 19 && i >= a.off[t + 1]) ++t;
        const int local = i - a.off[t];
        float v = bf ? bf2f(((const ush*)a.src[t])[local])
                     : ((const float*)a.src[t])[local];
        if (t < 16) {
            const int col = local % 192;
            if (col < 128) v *= -1.4426950408889634f;
            else if (t >= 8) v *= 2.885390081777927f;
        }
        arena[i] = f2bf(v);
    }
}

// ---------------------------------------------------------------------------
// Layer 1 (R1-proven version, ~33us/launch): bidirectional GRU(64), relu
// candidate. 16 rows/block, 4 waves x 16 units; h via double-buffered LDS +
// LDS-only barrier; x staged in LDS (hi/lo bf16 split), depth-2 raw-bit
// prefetch with conversion deferred one step. grid (bchunk/16, 2), block 256.
// ---------------------------------------------------------------------------
__global__ __launch_bounds__(256, 1)
void gru1_kernel(const void* __restrict__ X, const void* __restrict__ h0f,
                 const void* __restrict__ h0b, int cb, int bchunk,
                 const ush* __restrict__ Wf, const ush* __restrict__ Uf,
                 const ush* __restrict__ bif, const ush* __restrict__ brf,
                 const ush* __restrict__ Wb, const ush* __restrict__ Ub,
                 const ush* __restrict__ bib, const ush* __restrict__ brb,
                 ush* __restrict__ seq)
{
    const int tid  = threadIdx.x;
    const int lane = tid & 63;
    const int wv   = tid >> 6;
    const int q    = lane >> 4;
    const int ln   = lane & 15;
    const int dir  = blockIdx.y;
    const int lb0  = blockIdx.x * 16;
    const int gb0  = cb + lb0;
    const int u    = wv * 16 + ln;

    const ush* W  = dir ? Wb  : Wf;
    const ush* U  = dir ? Ub  : Uf;
    const ush* bi = dir ? bib : bif;
    const ush* br = dir ? brb : brf;
    const void* h0 = dir ? h0b : h0f;

    __shared__ __align__(16) ush Ah[2][16][72];
    __shared__ __align__(16) ush Ax[2][16][40];
    __shared__ int s_cnt;

    const bool xbf = probe_bf16((const ush*)X, tid, &s_cnt);

    {
        ush* p = &Ax[0][0][0];
        for (int i = tid; i < 2 * 16 * 40; i += 256) p[i] = 0;
    }
    __syncthreads();

    {
        const int tx0 = dir ? 71 : 0;
        if (tid < 144) {
            int r = tid / 9, k = tid - 9 * r;
            size_t idx = ((size_t)(gb0 + r) * 72 + tx0) * 9 + k;
            ush hv, lv;
            if (xbf) { hv = ((const ush*)X)[idx]; lv = 0; }
            else { float v = ((const float*)X)[idx]; hv = f2bf(v); lv = f2bf(v - bf2f(hv)); }
            Ax[0][r][2 * k]     = hv;
            Ax[0][r][2 * k + 1] = lv;
        }
    }

    short8 bU[3][2];
    short8 bW[3];
#pragma unroll
    for (int g = 0; g < 3; ++g) {
        const int col = g * 64 + u;
#pragma unroll
        for (int ks = 0; ks < 2; ++ks) {
            short8 f;
#pragma unroll
            for (int j = 0; j < 8; ++j) {
                int kp = ks * 32 + q * 8 + j;
                f[j] = (short)U[(size_t)kp * 192 + col];
            }
            bU[g][ks] = f;
        }
        short8 fw;
#pragma unroll
        for (int j = 0; j < 8; ++j) {
            int kp = q * 8 + j;
            fw[j] = (kp < 18) ? (short)W[(size_t)(kp >> 1) * 192 + col] : (short)0;
        }
        bW[g] = fw;
    }

    const float bz  = bf2f(bi[u])       + bf2f(br[u]);        // pre-scaled
    const float brg = bf2f(bi[64 + u])  + bf2f(br[64 + u]);   // pre-scaled
    const float bih = bf2f(bi[128 + u]);                      // unscaled (relu)
    const float brh = bf2f(br[128 + u]);
    const f32x4 Cz  = {bz,  bz,  bz,  bz};
    const f32x4 Cr  = {brg, brg, brg, brg};
    const f32x4 Chx = {bih, bih, bih, bih};
    const f32x4 Chr = {brh, brh, brh, brh};

    float hreg[4];
#pragma unroll
    for (int i = 0; i < 4; ++i) {
        int m = q * 4 + i;
        size_t idx = (size_t)(gb0 + m) * 64 + u;
        float hv = xbf ? bf2f(((const ush*)h0)[idx])
                       : ((const float*)h0)[idx];
        hreg[i] = hv;
        Ah[0][m][u] = f2bf(hv);
    }

    const int r2 = tid >> 3, c2 = tid & 7;
    const int r0x = tid / 9, k0x = tid - 9 * r0x;

    // depth-2 x pipeline, raw bits: craw holds x(t+1); conversion to bf16
    // hi/lo happens at the LDS-write point one step later.
    unsigned int craw = 0;
    if (tid < 144) {
        const int tx = dir ? 70 : 1;
        size_t idx = ((size_t)(gb0 + r0x) * 72 + tx) * 9 + k0x;
        craw = xbf ? (unsigned int)((const ush*)X)[idx]
                   : ((const unsigned int*)X)[idx];
    }
    __syncthreads();

#pragma unroll 2
    for (int t = 0; t < 72; ++t) {
        const int cur = t & 1, nb = cur ^ 1;

        unsigned int fraw = 0;
        if (t < 70 && tid < 144) {
            const int tx = dir ? (69 - t) : (t + 2);
            size_t idx = ((size_t)(gb0 + r0x) * 72 + tx) * 9 + k0x;
            fraw = xbf ? (unsigned int)((const ush*)X)[idx]
                       : ((const unsigned int*)X)[idx];
        }

        if (t > 0 && tid < 128) {
            const int tw = dir ? (71 - (t - 1)) : (t - 1);
            int4 v = *(const int4*)&Ah[cur][r2][c2 * 8];
            *(int4*)(seq + ((size_t)tw * bchunk + lb0 + r2) * 128 + dir * 64 + c2 * 8) = v;
        }

        const ush* ap = &Ah[cur][ln][0];
        short8 a0 = *(const short8*)(ap + q * 8);
        short8 a1 = *(const short8*)(ap + 32 + q * 8);
        short8 ax = *(const short8*)(&Ax[cur][ln][q * 8]);
        f32x4 az  = MFMA_B16(ax, bW[0], Cz);
        az        = MFMA_B16(a0, bU[0][0], az);
        az        = MFMA_B16(a1, bU[0][1], az);
        f32x4 ar  = MFMA_B16(ax, bW[1], Cr);
        ar        = MFMA_B16(a0, bU[1][0], ar);
        ar        = MFMA_B16(a1, bU[1][1], ar);
        f32x4 ahx = MFMA_B16(ax, bW[2], Chx);
        f32x4 ahr = MFMA_B16(a0, bU[2][0], Chr);
        ahr       = MFMA_B16(a1, bU[2][1], ahr);

#pragma unroll
        for (int i = 0; i < 4; ++i) {
            const int m = q * 4 + i;
            float z = sigm_pre(az[i]);
            float r = sigm_pre(ar[i]);
            float pre = ahx[i] + r * ahr[i];
            float hh = fmaxf(pre, 0.0f);
            float hn = hh + z * (hreg[i] - hh);
            hreg[i] = hn;
            Ah[nb][m][u] = f2bf(hn);
        }

        if (t < 71 && tid < 144) {
            ush hv, lv;
            if (xbf) { hv = (ush)craw; lv = 0; }
            else {
                float v = __uint_as_float(craw);
                hv = f2bf(v); lv = f2bf(v - bf2f(hv));
            }
            Ax[nb][r0x][2 * k0x]     = hv;
            Ax[nb][r0x][2 * k0x + 1] = lv;
        }
        craw = fraw;
        lds_barrier();
    }

    if (tid < 128) {
        const int tw = dir ? 0 : 71;
        int4 v = *(const int4*)&Ah[0][r2][c2 * 8];
        *(int4*)(seq + ((size_t)tw * bchunk + lb0 + r2) * 128 + dir * 64 + c2 * 8) = v;
    }
}

// ---------------------------------------------------------------------------
// Layer 2: bidirectional GRU(64), tanh (pre-scaled). 512-thread blocks:
// waves 0..3 = PRODUCERS (x-projections P(t+1), 12 MFMAs, zero-mov even/odd
// seq prefetch regs), waves 4..7 = CONSUMERS (recurrence + gates for unit
// tile wv-4). Wave w and w+4 share a SIMD (round-robin) -> two independent
// chains with complementary pipes interleave per SIMD. Double-buffered Pbuf
// and Ah; one LDS-only barrier per step. grid (bchunk/16, 2), block 512.
// ---------------------------------------------------------------------------
#define PCOMPUTE(E, BUFI)                                                      \
    do {                                                                       \
        f32x4 p0 = MFMA_B16(E##0, bV[0][0], Cg0);                              \
        p0 = MFMA_B16(E##1, bV[0][1], p0);                                     \
        p0 = MFMA_B16(E##2, bV[0][2], p0);                                     \
        p0 = MFMA_B16(E##3, bV[0][3], p0);                                     \
        *(f32x4*)&Pbuf[BUFI][0][pn][poff] = p0;                                \
        f32x4 p1 = MFMA_B16(E##0, bV[1][0], Cg1);                              \
        p1 = MFMA_B16(E##1, bV[1][1], p1);                                     \
        p1 = MFMA_B16(E##2, bV[1][2], p1);                                     \
        p1 = MFMA_B16(E##3, bV[1][3], p1);                                     \
        *(f32x4*)&Pbuf[BUFI][1][pn][poff] = p1;                                \
        f32x4 p2 = MFMA_B16(E##0, bV[2][0], Cg2);                              \
        p2 = MFMA_B16(E##1, bV[2][1], p2);                                     \
        p2 = MFMA_B16(E##2, bV[2][2], p2);                                     \
        p2 = MFMA_B16(E##3, bV[2][3], p2);                                     \
        *(f32x4*)&Pbuf[BUFI][2][pn][poff] = p2;                                \
    } while (0)

#define ELOAD(E, T)                                                            \
    do {                                                                       \
        const ush* sp_ = sptr0 + (long long)(T) * tstride;                     \
        E##0 = *(const short8*)(sp_);                                          \
        E##1 = *(const short8*)(sp_ + 32);                                     \
        E##2 = *(const short8*)(sp_ + 64);                                     \
        E##3 = *(const short8*)(sp_ + 96);                                     \
    } while (0)

__global__ __launch_bounds__(512, 1)
void gru2_kernel(const ush* __restrict__ seq, int cb, int bchunk,
                 const ush* __restrict__ W2f, const ush* __restrict__ U2f,
                 const ush* __restrict__ bi2f, const ush* __restrict__ br2f,
                 const ush* __restrict__ W2b, const ush* __restrict__ U2b,
                 const ush* __restrict__ bi2b, const ush* __restrict__ br2b,
                 float* __restrict__ feat)
{
    const int tid  = threadIdx.x;
    const int wv   = tid >> 6;
    const int lane = tid & 63;
    const int q    = lane >> 4;
    const int ln   = lane & 15;
    const int dir  = blockIdx.y;
    const int lb0  = blockIdx.x * 16;
    const int gb0  = cb + lb0;

    const ush* W  = dir ? W2b  : W2f;
    const ush* U  = dir ? U2b  : U2f;
    const ush* bi = dir ? bi2b : bi2f;
    const ush* br = dir ? br2b : br2f;

    // Pbuf: per (buf,gate,tile): 8 groups of (8 lanes x 16B) + 16B pad
    __shared__ __align__(16) float Pbuf[2][3][4][288];
    __shared__ __align__(16) ush Ah[2][16][72];

    const int poff = (lane >> 3) * 36 + (lane & 7) * 4;

    if (wv < 4) {
        // ---------------- producers: P(t) = x(t) @ W + bias ----------------
        const int pn = wv;                       // unit tile
        const int u2 = pn * 16 + ln;

        short8 bV[3][4];
#pragma unroll
        for (int g = 0; g < 3; ++g) {
            const int col = g * 64 + u2;
#pragma unroll
            for (int ks = 0; ks < 4; ++ks) {
                short8 f;
#pragma unroll
                for (int j = 0; j < 8; ++j) {
                    int kp = ks * 32 + q * 8 + j;
                    f[j] = (short)W[(size_t)kp * 192 + col];
                }
                bV[g][ks] = f;
            }
        }
        const float bz  = bf2f(bi[u2]) + bf2f(br[u2]);
        const float brg = bf2f(bi[64 + u2]) + bf2f(br[64 + u2]);
        const float bih = bf2f(bi[128 + u2]);
        const f32x4 Cg0 = {bz, bz, bz, bz};
        const f32x4 Cg1 = {brg, brg, brg, brg};
        const f32x4 Cg2 = {bih, bih, bih, bih};

        const long long tstride = (long long)bchunk * 128 * (dir ? -1 : 1);
        const ush* sptr0 = seq + (size_t)(lb0 + ln) * 128 + q * 8
                         + (dir ? 71ll * bchunk * 128 : 0);

        short8 EA0, EA1, EA2, EA3, EB0, EB1, EB2, EB3;
        // P(0) -> buf0 (reuse EA regs for s(0))
        ELOAD(EA, 0);
        PCOMPUTE(EA, 0);
        ELOAD(EA, 1);                            // consumed at t=0 -> P(1)
        ELOAD(EB, 2);                            // consumed at t=1 -> P(2)
        lds_barrier();

        for (int t = 0; t < 72; t += 2) {
            // even body: P(t+1) from EA -> buf1; EA <- s(t+3)
            PCOMPUTE(EA, 1);
            if (t <= 68) ELOAD(EA, t + 3);
            lds_barrier();
            // odd body: P(t+2) from EB -> buf0; EB <- s(t+4)
            if (t + 1 < 71) PCOMPUTE(EB, 0);
            if (t + 1 <= 68) ELOAD(EB, t + 4);
            lds_barrier();
        }
    } else {
        // ---------------- consumers: recurrence + gates ----------------
        const int cn = wv - 4;                   // unit tile
        const int u2 = cn * 16 + ln;

        short8 bU[3][2];
#pragma unroll
        for (int g = 0; g < 3; ++g) {
            const int col = g * 64 + u2;
#pragma unroll
            for (int ks = 0; ks < 2; ++ks) {
                short8 f;
#pragma unroll
                for (int j = 0; j < 8; ++j) {
                    int kp = ks * 32 + q * 8 + j;
                    f[j] = (short)U[(size_t)kp * 192 + col];
                }
                bU[g][ks] = f;
            }
        }
        const float brh = bf2f(br[128 + u2]);
        const f32x4 Chr = {brh, brh, brh, brh};

        // h(0) = 0
        for (int i = tid - 256; i < 16 * 72; i += 256) (&Ah[0][0][0])[i] = 0;
        float hreg[4];
#pragma unroll
        for (int i = 0; i < 4; ++i) hreg[i] = 0.0f;
        lds_barrier();

        for (int t = 0; t < 72; ++t) {
            const int cur = t & 1, nb = cur ^ 1;

            f32x4 Pz = *(const f32x4*)&Pbuf[cur][0][cn][poff];
            f32x4 Pr = *(const f32x4*)&Pbuf[cur][1][cn][poff];
            f32x4 Pc = *(const f32x4*)&Pbuf[cur][2][cn][poff];

            const ush* ap = &Ah[cur][ln][0];
            short8 a0 = *(const short8*)(ap + q * 8);
            short8 a1 = *(const short8*)(ap + 32 + q * 8);

            f32x4 az  = MFMA_B16(a0, bU[0][0], Pz);
            az        = MFMA_B16(a1, bU[0][1], az);
            f32x4 ar  = MFMA_B16(a0, bU[1][0], Pr);
            ar        = MFMA_B16(a1, bU[1][1], ar);
            f32x4 ahr = MFMA_B16(a0, bU[2][0], Chr);
            ahr       = MFMA_B16(a1, bU[2][1], ahr);

#pragma unroll
            for (int i = 0; i < 4; ++i) {
                const int m = q * 4 + i;
                float z = sigm_pre(az[i]);
                float r = sigm_pre(ar[i]);
                float pre = Pc[i] + r * ahr[i];
                float hh = tanh_pre(pre);
                float hn = hh + z * (hreg[i] - hh);
                hreg[i] = hn;
                Ah[nb][m][u2] = f2bf(hn);
            }
            lds_barrier();
        }

#pragma unroll
        for (int i = 0; i < 4; ++i) {
            const int m = q * 4 + i;
            feat[(size_t)(gb0 + m) * 128 + dir * 64 + u2] = hreg[i];
        }
    }
}

// ---------------------------------------------------------------------------
__global__ __launch_bounds__(256, 1)
void head_kernel(const float* __restrict__ feat,
                 const ush* __restrict__ dW, const ush* __restrict__ db,
                 const ush* __restrict__ oW, const ush* __restrict__ ob,
                 float* __restrict__ out)
{
    const int tid = threadIdx.x;
    const int b0  = blockIdx.x * 16;

    __shared__ __align__(16) ush Wl[128][136];
    __shared__ __align__(16) float fs[16][128];
    __shared__ __align__(16) float hs[16][136];
    __shared__ __align__(16) float ls[16][32];

    for (int i = tid; i < 2048; i += 256) {
        const int k = i >> 4;
        const int c = (i & 15) * 8;
        *(int4*)&Wl[k][c] = *(const int4*)(dW + (size_t)k * 128 + c);
    }
    {
        const float4* src = (const float4*)(feat + (size_t)b0 * 128);
        float4* dst = (float4*)&fs[0][0];
        for (int i = tid; i < 512; i += 256) dst[i] = src[i];
    }
    __syncthreads();

    {
        const int row = tid >> 4;
        const int j0  = (tid & 15) * 8;
        float acc[8];
#pragma unroll
        for (int jj = 0; jj < 8; ++jj) acc[jj] = bf2f(db[j0 + jj]);
        for (int k = 0; k < 128; ++k) {
            float f = fs[row][k];
            short8 w = *(const short8*)&Wl[k][j0];
#pragma unroll
            for (int jj = 0; jj < 8; ++jj)
                acc[jj] += f * bf2f((ush)w[jj]);
        }
#pragma unroll
        for (int jj = 0; jj < 8; ++jj) hs[row][j0 + jj] = fmaxf(acc[jj], 0.0f);
    }
    __syncthreads();

    for (int e = tid; e < 16 * 24; e += 256) {
        const int row = e / 24, l = e - 24 * row;
        float acc = bf2f(ob[l]);
        for (int k = 0; k < 128; ++k)
            acc += hs[row][k] * bf2f(oW[(size_t)k * 24 + l]);
        ls[row][l] = acc;
    }
    __syncthreads();

    for (int e = tid; e < 16 * 24; e += 256) {
        const int row = e / 24, l = e - 24 * row;
        float mx = ls[row][0];
#pragma unroll
        for (int k = 1; k < 24; ++k) mx = fmaxf(mx, ls[row][k]);
        float s = 0.0f;
#pragma unroll
        for (int k = 0; k < 24; ++k) s += __expf(ls[row][k] - mx);
        float v = __expf(ls[row][l] - mx) * rcp_f(s);
        out[(size_t)(b0 + row) * 24 + l] = v;
    }
}

// ---------------------------------------------------------------------------
extern "C" void kernel_launch(void* const* d_in, const int* in_sizes, int n_in,
                              void* d_out, int out_size, void* d_ws, size_t ws_size,
                              hipStream_t stream) {
    (void)in_sizes; (void)n_in; (void)out_size;

    static const int wc[20] = {
        1728, 12288, 192, 192,     // d1f W,U,bi,br   (t 0..3)
        1728, 12288, 192, 192,     // d1b             (t 4..7)
        24576, 12288, 192, 192,    // d2f             (t 8..11)
        24576, 12288, 192, 192,    // d2b             (t 12..15)
        16384, 128,                // dense           (t 16,17)
        3072, 24                   // out             (t 18,19)
    };

    WArgs a;
    int off = 0;
    for (int t = 0; t < 20; ++t) {
        a.src[t] = d_in[t + 3];
        a.off[t] = off;
        off += wc[t];
    }
    a.off[20] = off;                         // 122,904 elements

    const unsigned long long arena_bytes = 245952ull;
    const unsigned long long feat_bytes  = 4096ull * 128ull * 4ull;
    const unsigned long long seq_full    = 72ull * 4096ull * 128ull * 2ull;
    const unsigned long long fixed       = arena_bytes + feat_bytes;

    int nc = 32;
    for (int c = 1; c <= 32; c *= 2) {
        if (fixed + seq_full / (unsigned long long)c <= (unsigned long long)ws_size) { nc = c; break; }
    }
    const int bchunk = 4096 / nc;

    ush* arena  = (ush*)d_ws;
    float* feat = (float*)((char*)d_ws + arena_bytes);
    ush* seq    = (ush*)((char*)d_ws + fixed);

    convert_w<<<128, 256, 0, stream>>>(a, arena, (const ush*)d_in[0]);

    const ush* d1fW = arena + a.off[0];
    const ush* d1fU = arena + a.off[1];
    const ush* d1fbi= arena + a.off[2];
    const ush* d1fbr= arena + a.off[3];
    const ush* d1bW = arena + a.off[4];
    const ush* d1bU = arena + a.off[5];
    const ush* d1bbi= arena + a.off[6];
    const ush* d1bbr= arena + a.off[7];
    const ush* d2fW = arena + a.off[8];
    const ush* d2fU = arena + a.off[9];
    const ush* d2fbi= arena + a.off[10];
    const ush* d2fbr= arena + a.off[11];
    const ush* d2bW = arena + a.off[12];
    const ush* d2bU = arena + a.off[13];
    const ush* d2bbi= arena + a.off[14];
    const ush* d2bbr= arena + a.off[15];
    const ush* dW   = arena + a.off[16];
    const ush* db   = arena + a.off[17];
    const ush* oW   = arena + a.off[18];
    const ush* ob   = arena + a.off[19];

    for (int c = 0; c < nc; ++c) {
        const int cb = c * bchunk;
        gru1_kernel<<<dim3(bchunk / 16, 2), 256, 0, stream>>>(
            d_in[0], d_in[1], d_in[2], cb, bchunk,
            d1fW, d1fU, d1fbi, d1fbr, d1bW, d1bU, d1bbi, d1bbr, seq);
        gru2_kernel<<<dim3(bchunk / 16, 2), 512, 0, stream>>>(
            seq, cb, bchunk,
            d2fW, d2fU, d2fbi, d2fbr, d2bW, d2bU, d2bbi, d2bbr, feat);
    }
    head_kernel<<<256, 256, 0, stream>>>(
        feat, dW, db, oW, ob, (float*)d_out);
}